// Round 1
// baseline (171.152 us; speedup 1.0000x reference)
//
#include <hip/hip_runtime.h>

#define NPTS 1048576
#define NOUT 128
#define NPAR 64
#define BLOCK 256
#define PPT 4          // points per thread
#define STR 132        // LDS row stride in floats: 132*4=528 bytes = 33*16 -> keeps 16B align,
                       // and row*132 mod 32 banks cycles through 8 bank-groups (vs 1 for 128)

__global__ __launch_bounds__(BLOCK, 4)
void kan_kernel(const float* __restrict__ x,
                const float* __restrict__ params,
                float* __restrict__ out) {
    __shared__ float sP[NPAR * STR];

    const int tid = threadIdx.x;

    // Stage params [64][128] -> LDS [64][STR], float4 coalesced
    {
        const float4* p4 = (const float4*)params;
        #pragma unroll
        for (int g = tid; g < NPAR * (NOUT / 4); g += BLOCK) {
            float4 v = p4[g];
            *(float4*)&sP[(g >> 5) * STR + (g & 31) * 4] = v;
        }
    }
    __syncthreads();

    const int base = blockIdx.x * (BLOCK * PPT) + tid * PPT;
    const float4 xv = *(const float4*)(x + base);
    float xs[PPT] = {xv.x, xv.y, xv.z, xv.w};

    float b[PPT][4];    // 4 nonzero cubic basis values per point
    float sil[PPT];     // silu(x)
    int   rbase[PPT];   // first param row (0..59 -> rows rbase..rbase+3, max 62)

    #pragma unroll
    for (int pp = 0; pp < PPT; ++pp) {
        float xx = xs[pp];
        sil[pp] = xx / (1.0f + __expf(-xx));

        float inr = (xx >= -3.0f && xx < 3.0f) ? 1.0f : 0.0f;
        float u = (xx + 3.0f) * 10.0f;   // interior knot spacing = 0.1
        int si = (int)u;
        si = si < 0 ? 0 : (si > 59 ? 59 : si);

        // Knot values around span i = si+3 (clamped uniform knots on [-3,3])
        float Ki   = -3.0f + 0.1f * (float)si;
        float Kim1 = -3.0f + 0.1f * (float)(si - 1 > 0 ? si - 1 : 0);
        float Kim2 = -3.0f + 0.1f * (float)(si - 2 > 0 ? si - 2 : 0);
        float Kip1 = -3.0f + 0.1f * (float)(si + 1);
        float Kip2 = -3.0f + 0.1f * (float)(si + 2 < 60 ? si + 2 : 60);
        float Kip3 = -3.0f + 0.1f * (float)(si + 3 < 60 ? si + 3 : 60);

        float l1 = xx - Ki,   r1 = Kip1 - xx;
        float l2 = xx - Kim1, r2 = Kip2 - xx;
        float l3 = xx - Kim2, r3 = Kip3 - xx;

        // De Boor (Cox-de Boor basis funcs), degree 3; denominators > 0 always
        float N0 = 1.0f, N1, N2, N3, t, saved;
        // d=1
        t = N0 / (r1 + l1); N0 = r1 * t; N1 = l1 * t;
        // d=2
        t = N0 / (r1 + l2); N0 = r1 * t;          saved = l2 * t;
        t = N1 / (r2 + l1); N1 = saved + r2 * t;  N2    = l1 * t;
        // d=3
        t = N0 / (r1 + l3); N0 = r1 * t;          saved = l3 * t;
        t = N1 / (r2 + l2); N1 = saved + r2 * t;  saved = l2 * t;
        t = N2 / (r3 + l1); N2 = saved + r3 * t;  N3    = l1 * t;

        b[pp][0] = N0 * inr;
        b[pp][1] = N1 * inr;
        b[pp][2] = N2 * inr;
        b[pp][3] = N3 * inr;
        rbase[pp] = si;
    }

    float* outc = out + base;

    #pragma unroll 2
    for (int j0 = 0; j0 < NOUT; j0 += 4) {
        // silu row: wave-uniform address -> LDS broadcast, conflict-free
        float4 p63 = *(const float4*)&sP[63 * STR + j0];

        float a[PPT][4];
        #pragma unroll
        for (int pp = 0; pp < PPT; ++pp) {
            const float* rp = &sP[rbase[pp] * STR + j0];
            float4 q0 = *(const float4*)(rp);
            float4 q1 = *(const float4*)(rp + STR);
            float4 q2 = *(const float4*)(rp + 2 * STR);
            float4 q3 = *(const float4*)(rp + 3 * STR);
            float b0 = b[pp][0], b1 = b[pp][1], b2 = b[pp][2], b3 = b[pp][3];
            float s = sil[pp];
            a[pp][0] = s * p63.x + b0 * q0.x + b1 * q1.x + b2 * q2.x + b3 * q3.x;
            a[pp][1] = s * p63.y + b0 * q0.y + b1 * q1.y + b2 * q2.y + b3 * q3.y;
            a[pp][2] = s * p63.z + b0 * q0.z + b1 * q1.z + b2 * q2.z + b3 * q3.z;
            a[pp][3] = s * p63.w + b0 * q0.w + b1 * q1.w + b2 * q2.w + b3 * q3.w;
        }

        // 4x4 register transpose -> coalesced float4 stores per output row
        #pragma unroll
        for (int jj = 0; jj < 4; ++jj) {
            float4 v = make_float4(a[0][jj], a[1][jj], a[2][jj], a[3][jj]);
            *(float4*)(outc + (size_t)(j0 + jj) * NPTS) = v;
        }
    }
}

extern "C" void kernel_launch(void* const* d_in, const int* in_sizes, int n_in,
                              void* d_out, int out_size, void* d_ws, size_t ws_size,
                              hipStream_t stream) {
    const float* x      = (const float*)d_in[0];
    const float* params = (const float*)d_in[1];
    float* out          = (float*)d_out;

    dim3 grid(NPTS / (BLOCK * PPT));   // 1024 blocks
    kan_kernel<<<grid, BLOCK, 0, stream>>>(x, params, out);
}

// Round 3
// 120.843 us; speedup vs baseline: 1.4163x; 1.4163x over previous
//
#include <hip/hip_runtime.h>

#define NPTS 1048576
#define NOUT 128
#define NPAR 64
#define BLOCK 256
#define PPT 4            // points per thread
#define STRH 136         // LDS row stride in bf16 elems: 272 B = 17*16 -> 16B-aligned rows,
                         // row*272/4 mod 32 = row*4 mod 32 -> rows cycle 8 bank-groups

typedef float vf4 __attribute__((ext_vector_type(4)));   // native vector for nontemporal store

__device__ __forceinline__ unsigned short f2bf(float f) {
    unsigned int u = __float_as_uint(f);
    u += 0x7fffu + ((u >> 16) & 1u);   // round-to-nearest-even
    return (unsigned short)(u >> 16);
}

__device__ __forceinline__ void bf2x(unsigned int u, float& lo, float& hi) {
    lo = __uint_as_float(u << 16);
    hi = __uint_as_float(u & 0xffff0000u);
}

__global__ __launch_bounds__(BLOCK, 4)
void kan_kernel(const float* __restrict__ x,
                const float* __restrict__ params,
                float* __restrict__ out) {
    __shared__ unsigned short sH[NPAR * STRH];

    const int tid = threadIdx.x;

    // Stage params [64][128] f32 -> LDS bf16 [64][STRH], coalesced float4 reads
    {
        const float4* p4 = (const float4*)params;
        #pragma unroll
        for (int g = tid; g < NPAR * (NOUT / 4); g += BLOCK) {
            float4 v = p4[g];
            ushort4 h;
            h.x = f2bf(v.x); h.y = f2bf(v.y); h.z = f2bf(v.z); h.w = f2bf(v.w);
            *(ushort4*)&sH[(g >> 5) * STRH + (g & 31) * 4] = h;
        }
    }
    __syncthreads();

    const int base = blockIdx.x * (BLOCK * PPT) + tid * PPT;
    const float4 xv = *(const float4*)(x + base);
    float xs[PPT] = {xv.x, xv.y, xv.z, xv.w};

    float b[PPT][4];    // 4 nonzero cubic basis values per point
    float sil[PPT];     // silu(x)
    int   rbase[PPT];   // first param row

    #pragma unroll
    for (int pp = 0; pp < PPT; ++pp) {
        float xx = xs[pp];
        sil[pp] = xx / (1.0f + __expf(-xx));

        float inr = (xx >= -3.0f && xx < 3.0f) ? 1.0f : 0.0f;
        float u = (xx + 3.0f) * 10.0f;   // interior knot spacing = 0.1
        int si = (int)u;
        si = si < 0 ? 0 : (si > 59 ? 59 : si);

        // Clamped uniform knots on [-3,3], spacing 0.1
        float Ki   = -3.0f + 0.1f * (float)si;
        float Kim1 = -3.0f + 0.1f * (float)(si - 1 > 0 ? si - 1 : 0);
        float Kim2 = -3.0f + 0.1f * (float)(si - 2 > 0 ? si - 2 : 0);
        float Kip1 = -3.0f + 0.1f * (float)(si + 1);
        float Kip2 = -3.0f + 0.1f * (float)(si + 2 < 60 ? si + 2 : 60);
        float Kip3 = -3.0f + 0.1f * (float)(si + 3 < 60 ? si + 3 : 60);

        float l1 = xx - Ki,   r1 = Kip1 - xx;
        float l2 = xx - Kim1, r2 = Kip2 - xx;
        float l3 = xx - Kim2, r3 = Kip3 - xx;

        // Cox-de Boor, degree 3 (denominators always > 0)
        float N0 = 1.0f, N1, N2, N3, t, saved;
        t = N0 / (r1 + l1); N0 = r1 * t; N1 = l1 * t;
        t = N0 / (r1 + l2); N0 = r1 * t;          saved = l2 * t;
        t = N1 / (r2 + l1); N1 = saved + r2 * t;  N2    = l1 * t;
        t = N0 / (r1 + l3); N0 = r1 * t;          saved = l3 * t;
        t = N1 / (r2 + l2); N1 = saved + r2 * t;  saved = l2 * t;
        t = N2 / (r3 + l1); N2 = saved + r3 * t;  N3    = l1 * t;

        b[pp][0] = N0 * inr;
        b[pp][1] = N1 * inr;
        b[pp][2] = N2 * inr;
        b[pp][3] = N3 * inr;
        rbase[pp] = si;
    }

    float* outc = out + base;

    #pragma unroll 2
    for (int j0 = 0; j0 < NOUT; j0 += 8) {
        // silu row: wave-uniform address -> LDS broadcast
        uint4 u63 = *(const uint4*)&sH[63 * STRH + j0];
        float p63f[8];
        bf2x(u63.x, p63f[0], p63f[1]);
        bf2x(u63.y, p63f[2], p63f[3]);
        bf2x(u63.z, p63f[4], p63f[5]);
        bf2x(u63.w, p63f[6], p63f[7]);

        float a[PPT][8];
        #pragma unroll
        for (int pp = 0; pp < PPT; ++pp) {
            const unsigned short* rp = &sH[rbase[pp] * STRH + j0];
            uint4 q0 = *(const uint4*)(rp);
            uint4 q1 = *(const uint4*)(rp + STRH);
            uint4 q2 = *(const uint4*)(rp + 2 * STRH);
            uint4 q3 = *(const uint4*)(rp + 3 * STRH);

            float f0[8], f1[8], f2[8], f3[8];
            bf2x(q0.x, f0[0], f0[1]); bf2x(q0.y, f0[2], f0[3]);
            bf2x(q0.z, f0[4], f0[5]); bf2x(q0.w, f0[6], f0[7]);
            bf2x(q1.x, f1[0], f1[1]); bf2x(q1.y, f1[2], f1[3]);
            bf2x(q1.z, f1[4], f1[5]); bf2x(q1.w, f1[6], f1[7]);
            bf2x(q2.x, f2[0], f2[1]); bf2x(q2.y, f2[2], f2[3]);
            bf2x(q2.z, f2[4], f2[5]); bf2x(q2.w, f2[6], f2[7]);
            bf2x(q3.x, f3[0], f3[1]); bf2x(q3.y, f3[2], f3[3]);
            bf2x(q3.z, f3[4], f3[5]); bf2x(q3.w, f3[6], f3[7]);

            float b0 = b[pp][0], b1 = b[pp][1], b2 = b[pp][2], b3 = b[pp][3];
            float s = sil[pp];
            #pragma unroll
            for (int c = 0; c < 8; ++c) {
                float acc = s * p63f[c];
                acc = fmaf(b0, f0[c], acc);
                acc = fmaf(b1, f1[c], acc);
                acc = fmaf(b2, f2[c], acc);
                acc = fmaf(b3, f3[c], acc);
                a[pp][c] = acc;
            }
        }

        // 4x4 register transpose -> coalesced nontemporal vf4 stores
        #pragma unroll
        for (int c = 0; c < 8; ++c) {
            vf4 v = { a[0][c], a[1][c], a[2][c], a[3][c] };
            __builtin_nontemporal_store(v, (vf4*)(outc + (size_t)(j0 + c) * NPTS));
        }
    }
}

extern "C" void kernel_launch(void* const* d_in, const int* in_sizes, int n_in,
                              void* d_out, int out_size, void* d_ws, size_t ws_size,
                              hipStream_t stream) {
    const float* x      = (const float*)d_in[0];
    const float* params = (const float*)d_in[1];
    float* out          = (float*)d_out;

    dim3 grid(NPTS / (BLOCK * PPT));   // 1024 blocks
    kan_kernel<<<grid, BLOCK, 0, stream>>>(x, params, out);
}

// Round 4
// 120.718 us; speedup vs baseline: 1.4178x; 1.0010x over previous
//
#include <hip/hip_runtime.h>

#define NPTS 1048576
#define NOUT 128
#define NPAR 64
#define BLOCK 256
#define PPT 2            // points per thread
#define STRH 136         // LDS row stride in bf16: 272 B = 17*16 -> 16B-aligned rows,
                         // first-dword bank = row*4 mod 32 -> rows cycle 8 bank-groups

typedef float vf2 __attribute__((ext_vector_type(2)));   // native vector for nontemporal store

__device__ __forceinline__ unsigned short f2bf(float f) {
    unsigned int u = __float_as_uint(f);
    u += 0x7fffu + ((u >> 16) & 1u);   // round-to-nearest-even
    return (unsigned short)(u >> 16);
}

__device__ __forceinline__ void bf2x(unsigned int u, float& lo, float& hi) {
    lo = __uint_as_float(u << 16);
    hi = __uint_as_float(u & 0xffff0000u);
}

__global__ __launch_bounds__(BLOCK, 8)   // 8 waves/EU -> 64-VGPR budget, 32 waves/CU
void kan_kernel(const float* __restrict__ x,
                const float* __restrict__ params,
                float* __restrict__ out) {
    __shared__ unsigned short sH[NPAR * STRH];

    const int tid = threadIdx.x;

    // Stage params [64][128] f32 -> LDS bf16 [64][STRH]
    {
        const float4* p4 = (const float4*)params;
        #pragma unroll
        for (int g = tid; g < NPAR * (NOUT / 4); g += BLOCK) {
            float4 v = p4[g];
            ushort4 h;
            h.x = f2bf(v.x); h.y = f2bf(v.y); h.z = f2bf(v.z); h.w = f2bf(v.w);
            *(ushort4*)&sH[(g >> 5) * STRH + (g & 31) * 4] = h;
        }
    }
    __syncthreads();

    const int base = blockIdx.x * (BLOCK * PPT) + tid * PPT;
    const float2 xv = *(const float2*)(x + base);
    float xs[PPT] = {xv.x, xv.y};

    float b[PPT][4];
    float sil[PPT];
    int   rbase[PPT];

    #pragma unroll
    for (int pp = 0; pp < PPT; ++pp) {
        float xx = xs[pp];
        sil[pp] = xx / (1.0f + __expf(-xx));

        float inr = (xx >= -3.0f && xx < 3.0f) ? 1.0f : 0.0f;
        float u = (xx + 3.0f) * 10.0f;
        int si = (int)u;
        si = si < 0 ? 0 : (si > 59 ? 59 : si);

        float Ki   = -3.0f + 0.1f * (float)si;
        float Kim1 = -3.0f + 0.1f * (float)(si - 1 > 0 ? si - 1 : 0);
        float Kim2 = -3.0f + 0.1f * (float)(si - 2 > 0 ? si - 2 : 0);
        float Kip1 = -3.0f + 0.1f * (float)(si + 1);
        float Kip2 = -3.0f + 0.1f * (float)(si + 2 < 60 ? si + 2 : 60);
        float Kip3 = -3.0f + 0.1f * (float)(si + 3 < 60 ? si + 3 : 60);

        float l1 = xx - Ki,   r1 = Kip1 - xx;
        float l2 = xx - Kim1, r2 = Kip2 - xx;
        float l3 = xx - Kim2, r3 = Kip3 - xx;

        float N0 = 1.0f, N1, N2, N3, t, saved;
        t = N0 / (r1 + l1); N0 = r1 * t; N1 = l1 * t;
        t = N0 / (r1 + l2); N0 = r1 * t;          saved = l2 * t;
        t = N1 / (r2 + l1); N1 = saved + r2 * t;  N2    = l1 * t;
        t = N0 / (r1 + l3); N0 = r1 * t;          saved = l3 * t;
        t = N1 / (r2 + l2); N1 = saved + r2 * t;  saved = l2 * t;
        t = N2 / (r3 + l1); N2 = saved + r3 * t;  N3    = l1 * t;

        b[pp][0] = N0 * inr;
        b[pp][1] = N1 * inr;
        b[pp][2] = N2 * inr;
        b[pp][3] = N3 * inr;
        rbase[pp] = si;
    }

    float* outc = out + base;

    #pragma unroll 1    // keep VGPRs under the 8-waves/EU budget
    for (int j0 = 0; j0 < NOUT; j0 += 8) {
        // silu row: wave-uniform address -> LDS broadcast
        uint4 u63 = *(const uint4*)&sH[63 * STRH + j0];
        float p63f[8];
        bf2x(u63.x, p63f[0], p63f[1]);
        bf2x(u63.y, p63f[2], p63f[3]);
        bf2x(u63.z, p63f[4], p63f[5]);
        bf2x(u63.w, p63f[6], p63f[7]);

        float a[PPT][8];
        #pragma unroll
        for (int pp = 0; pp < PPT; ++pp) {
            const unsigned short* rp = &sH[rbase[pp] * STRH + j0];
            float s = sil[pp];
            float acc[8];
            #pragma unroll
            for (int c = 0; c < 8; ++c) acc[c] = s * p63f[c];

            // one param row at a time: keeps only 8 unpacked floats live
            #pragma unroll
            for (int r = 0; r < 4; ++r) {
                uint4 q = *(const uint4*)(rp + r * STRH);
                float f[8];
                bf2x(q.x, f[0], f[1]); bf2x(q.y, f[2], f[3]);
                bf2x(q.z, f[4], f[5]); bf2x(q.w, f[6], f[7]);
                float br = b[pp][r];
                #pragma unroll
                for (int c = 0; c < 8; ++c) acc[c] = fmaf(br, f[c], acc[c]);
            }
            #pragma unroll
            for (int c = 0; c < 8; ++c) a[pp][c] = acc[c];
        }

        // 2-wide register transpose -> coalesced nontemporal float2 stores
        #pragma unroll
        for (int c = 0; c < 8; ++c) {
            vf2 v = { a[0][c], a[1][c] };
            __builtin_nontemporal_store(v, (vf2*)(outc + (size_t)(j0 + c) * NPTS));
        }
    }
}

extern "C" void kernel_launch(void* const* d_in, const int* in_sizes, int n_in,
                              void* d_out, int out_size, void* d_ws, size_t ws_size,
                              hipStream_t stream) {
    const float* x      = (const float*)d_in[0];
    const float* params = (const float*)d_in[1];
    float* out          = (float*)d_out;

    dim3 grid(NPTS / (BLOCK * PPT));   // 2048 blocks -> 8/CU co-resident
    kan_kernel<<<grid, BLOCK, 0, stream>>>(x, params, out);
}

// Round 5
// 120.307 us; speedup vs baseline: 1.4226x; 1.0034x over previous
//
#include <hip/hip_runtime.h>

#define NPTS 1048576
#define NOUT 128
#define NPAR 64
#define BLOCK 256
#define PPT 4              // points per thread
#define CPB (BLOCK * PPT)  // 1024 points per block
#define STRH 136           // params LDS row stride in bf16 (272 B = 17*16, rows cycle 8 bank groups)
#define G 8                // output rows staged per tile
#define SST 1024           // staging row stride in f32 (both access phases are conflict-free by construction)

typedef float vf4 __attribute__((ext_vector_type(4)));

__device__ __forceinline__ unsigned short f2bf(float f) {
    unsigned int u = __float_as_uint(f);
    u += 0x7fffu + ((u >> 16) & 1u);   // round-to-nearest-even
    return (unsigned short)(u >> 16);
}

__device__ __forceinline__ void bf2x(unsigned int u, float& lo, float& hi) {
    lo = __uint_as_float(u << 16);
    hi = __uint_as_float(u & 0xffff0000u);
}

__global__ __launch_bounds__(BLOCK, 4)
void kan_kernel(const float* __restrict__ x,
                const float* __restrict__ params,
                float* __restrict__ out) {
    __shared__ unsigned short sH[NPAR * STRH];  // 17.4 KB params (bf16)
    __shared__ float sS[G * SST];               // 32 KB output staging

    const int tid = threadIdx.x;

    // Stage params [64][128] f32 -> LDS bf16
    {
        const float4* p4 = (const float4*)params;
        #pragma unroll
        for (int g = tid; g < NPAR * (NOUT / 4); g += BLOCK) {
            float4 v = p4[g];
            ushort4 h;
            h.x = f2bf(v.x); h.y = f2bf(v.y); h.z = f2bf(v.z); h.w = f2bf(v.w);
            *(ushort4*)&sH[(g >> 5) * STRH + (g & 31) * 4] = h;
        }
    }

    const int base = blockIdx.x * CPB + tid * PPT;
    const float4 xv = *(const float4*)(x + base);
    float xs[PPT] = {xv.x, xv.y, xv.z, xv.w};

    float b[PPT][4];
    float sil[PPT];
    int   rbase[PPT];

    #pragma unroll
    for (int pp = 0; pp < PPT; ++pp) {
        float xx = xs[pp];
        sil[pp] = xx / (1.0f + __expf(-xx));

        float inr = (xx >= -3.0f && xx < 3.0f) ? 1.0f : 0.0f;
        float u = (xx + 3.0f) * 10.0f;
        int si = (int)u;
        si = si < 0 ? 0 : (si > 59 ? 59 : si);

        float Ki   = -3.0f + 0.1f * (float)si;
        float Kim1 = -3.0f + 0.1f * (float)(si - 1 > 0 ? si - 1 : 0);
        float Kim2 = -3.0f + 0.1f * (float)(si - 2 > 0 ? si - 2 : 0);
        float Kip1 = -3.0f + 0.1f * (float)(si + 1);
        float Kip2 = -3.0f + 0.1f * (float)(si + 2 < 60 ? si + 2 : 60);
        float Kip3 = -3.0f + 0.1f * (float)(si + 3 < 60 ? si + 3 : 60);

        float l1 = xx - Ki,   r1 = Kip1 - xx;
        float l2 = xx - Kim1, r2 = Kip2 - xx;
        float l3 = xx - Kim2, r3 = Kip3 - xx;

        float N0 = 1.0f, N1, N2, N3, t, saved;
        t = N0 / (r1 + l1); N0 = r1 * t; N1 = l1 * t;
        t = N0 / (r1 + l2); N0 = r1 * t;          saved = l2 * t;
        t = N1 / (r2 + l1); N1 = saved + r2 * t;  N2    = l1 * t;
        t = N0 / (r1 + l3); N0 = r1 * t;          saved = l3 * t;
        t = N1 / (r2 + l2); N1 = saved + r2 * t;  saved = l2 * t;
        t = N2 / (r3 + l1); N2 = saved + r3 * t;  N3    = l1 * t;

        b[pp][0] = N0 * inr;
        b[pp][1] = N1 * inr;
        b[pp][2] = N2 * inr;
        b[pp][3] = N3 * inr;
        rbase[pp] = si;
    }

    __syncthreads();   // params staged

    const int w = tid >> 6;       // wave id (0..3)
    const int l = tid & 63;       // lane

    #pragma unroll 1
    for (int j0 = 0; j0 < NOUT; j0 += G) {
        // ---- compute phase: 8 cols for 4 points ----
        uint4 u63 = *(const uint4*)&sH[63 * STRH + j0];
        float p63f[8];
        bf2x(u63.x, p63f[0], p63f[1]);
        bf2x(u63.y, p63f[2], p63f[3]);
        bf2x(u63.z, p63f[4], p63f[5]);
        bf2x(u63.w, p63f[6], p63f[7]);

        float a[PPT][8];
        #pragma unroll
        for (int pp = 0; pp < PPT; ++pp) {
            const unsigned short* rp = &sH[rbase[pp] * STRH + j0];
            float s = sil[pp];
            float acc[8];
            #pragma unroll
            for (int c = 0; c < 8; ++c) acc[c] = s * p63f[c];

            #pragma unroll
            for (int r = 0; r < 4; ++r) {
                uint4 q = *(const uint4*)(rp + r * STRH);
                float f[8];
                bf2x(q.x, f[0], f[1]); bf2x(q.y, f[2], f[3]);
                bf2x(q.z, f[4], f[5]); bf2x(q.w, f[6], f[7]);
                float br = b[pp][r];
                #pragma unroll
                for (int c = 0; c < 8; ++c) acc[c] = fmaf(br, f[c], acc[c]);
            }
            #pragma unroll
            for (int c = 0; c < 8; ++c) a[pp][c] = acc[c];
        }

        // write staging: row c holds this block's 1024 points for output row j0+c
        #pragma unroll
        for (int c = 0; c < 8; ++c) {
            vf4 v = { a[0][c], a[1][c], a[2][c], a[3][c] };
            *(vf4*)&sS[c * SST + tid * 4] = v;
        }

        __syncthreads();

        // ---- drain phase: j-major, one 4 KiB contiguous row burst per wave-row ----
        #pragma unroll
        for (int rr = 0; rr < 2; ++rr) {
            const int r = 2 * w + rr;
            float* orow = out + (size_t)(j0 + r) * NPTS + blockIdx.x * CPB;
            #pragma unroll
            for (int k = 0; k < 4; ++k) {
                vf4 v = *(const vf4*)&sS[r * SST + k * 256 + l * 4];
                *(vf4*)(orow + k * 256 + l * 4) = v;
            }
        }

        __syncthreads();   // staging reusable
    }
}

extern "C" void kernel_launch(void* const* d_in, const int* in_sizes, int n_in,
                              void* d_out, int out_size, void* d_ws, size_t ws_size,
                              hipStream_t stream) {
    const float* x      = (const float*)d_in[0];
    const float* params = (const float*)d_in[1];
    float* out          = (float*)d_out;

    dim3 grid(NPTS / CPB);   // 1024 blocks
    kan_kernel<<<grid, BLOCK, 0, stream>>>(x, params, out);
}